// Round 22
// baseline (313.893 us; speedup 1.0000x reference)
//
#include <hip/hip_runtime.h>
#include <hip/hip_bf16.h>

// ---------------- problem constants ----------------
#define N_TOK 32768
#define DIMC  512
#define NH    8
#define DHD   64
#define NL    64
#define KSZ   33
#define QKVC  1536
#define NCHUNK 64   // attn3 chunks; 512 tokens per block

typedef _Float16 f16;
typedef _Float16 f16x8 __attribute__((ext_vector_type(8)));
typedef _Float16 f16x4 __attribute__((ext_vector_type(4)));
typedef _Float16 f16x2 __attribute__((ext_vector_type(2)));
typedef float    f32x4 __attribute__((ext_vector_type(4)));

#define GLOAD_LDS16(gp, lp) \
    __builtin_amdgcn_global_load_lds((const __attribute__((address_space(1))) void*)(gp), \
                                     (__attribute__((address_space(3))) void*)(lp), 16, 0, 0)

// ---------------- transpose f32 (R x C) -> f16 (C x R) ----------------
__global__ void transpose_k(const float* __restrict__ W, f16* __restrict__ WT, int R, int C) {
    __shared__ float tile[32][33];
    int bx = blockIdx.x * 32, by = blockIdx.y * 32;
    int tx = threadIdx.x, ty = threadIdx.y;
    #pragma unroll
    for (int i = 0; i < 32; i += 8)
        tile[ty + i][tx] = W[(size_t)(by + ty + i) * C + bx + tx];
    __syncthreads();
    #pragma unroll
    for (int i = 0; i < 32; i += 8)
        WT[(size_t)(bx + ty + i) * R + by + tx] = (f16)tile[tx][ty + i];
}

// ---------------- per-chunk label histogram + global counts ----------------
__global__ __launch_bounds__(256) void hist_chunk_k(const int* __restrict__ labels,
                                                    int* __restrict__ counts,
                                                    int* __restrict__ chunkCnt) {
    __shared__ int hloc[NL];
    int t = threadIdx.x, c = blockIdx.x;
    if (t < NL) hloc[t] = 0;
    __syncthreads();
    atomicAdd(&hloc[labels[c * 256 + t]], 1);
    __syncthreads();
    if (t < NL) {
        chunkCnt[c * NL + t] = hloc[t];
        atomicAdd(&counts[t], hloc[t]);
    }
}

// ---------------- scan: baseC[c][l] = globalBase[l] + sum_{c'<c} chunkCnt[c'][l] ----------------
__global__ void scan_all_k(const int* __restrict__ chunkCnt, const int* __restrict__ counts,
                           int* __restrict__ baseC, int* __restrict__ baseG) {
    int l = threadIdx.x;    // 64 threads
    int gb = 0;
    for (int j = 0; j < l; ++j) gb += counts[j];
    baseG[l] = gb;
    int run = gb;
    for (int c = 0; c < 128; ++c) {
        baseC[c * NL + l] = run;
        run += chunkCnt[c * NL + l];
    }
}

// ---------------- fully parallel stable placement (order = (label, index)) ----------------
__global__ __launch_bounds__(256) void place_k(const int* __restrict__ labels,
                                               const int* __restrict__ baseC,
                                               int* __restrict__ indexArr) {
    __shared__ int labs[256];
    int t = threadIdx.x, c = blockIdx.x;
    int ii = c * 256 + t;
    int lab = labels[ii];
    labs[t] = lab;
    __syncthreads();
    int rank = 0;
    for (int j = 0; j < 256; ++j)
        rank += (j < t && labs[j] == lab) ? 1 : 0;      // LDS broadcast reads, deterministic
    indexArr[baseC[c * NL + lab] + rank] = ii;
}

// ---------------- gather rows of x via index, convert to f16 (sorted domain) ----------------
__global__ __launch_bounds__(256) void gather_cvt_k(const float4* __restrict__ x4,
                                                    const int* __restrict__ indexArr,
                                                    f16x4* __restrict__ xh4) {
    int t = threadIdx.x;
    int row = blockIdx.x * 2 + (t >> 7);
    int c4 = t & 127;
    int j = indexArr[row];
    float4 v = x4[(size_t)j * 128 + c4];
    f16x4 o = { (f16)v.x, (f16)v.y, (f16)v.z, (f16)v.w };
    xh4[(size_t)row * 128 + c4] = o;
}

// ---------------- NEW: 256x256-tile deep-pipeline f16 GEMM (qkv projection only) ----------------
// Structural clone of the proven 3-buffer/counted-vmcnt skeleton, scaled:
// BK=32 sub-tiles, 4 LDS slots (128 KB, 1 block/CU), depth-3 prefetch, vmcnt(8/4/0),
// ONE barrier per K-step, 32 MFMA/step/wave (2x the old 16), same cg/kc swizzle pair,
// same T1 bijective XCD swizzle. Race invariants identical to gemm_k512:
//   stage(kt+3) writes slot (kt-1)&3 whose last reads (compute(kt-1)) finished before
//   this step's barrier; vmcnt(8) forces stage(kt) landed, leaves kt+1/kt+2 in flight.
template<int BNTOT, int NY>
__global__ __launch_bounds__(512, 2) void gemm256_k512(const f16* __restrict__ A,
                                                       const f16* __restrict__ BT,
                                                       f16* __restrict__ Cout) {
    constexpr int K = 512;
    constexpr int NKT = K / 32;             // 16 K-sub-tiles
    __shared__ f16 As[4][256 * 32];         // 4 x 16 KB
    __shared__ f16 Bs[4][256 * 32];         // 4 x 16 KB  (128 KB total)
    const int t = threadIdx.x;
    const int orig = blockIdx.x + gridDim.x * blockIdx.y;
    constexpr int NWG = 128 * NY;           // gridDim.x == 128 (N_TOK/256); NWG % 8 == 0
    constexpr int CPX = NWG / 8;
    const int lin = (orig & 7) * CPX + (orig >> 3);
    const int mBase = (lin / NY) * 256;
    const int nBase = (lin % NY) * 256;
    const int w = t >> 6, lane = t & 63;
    const int wm = w >> 2, wn = w & 3;      // 2 x 4 wave grid; wave tile 128(M) x 64(N)
    const int lr = lane & 15, lk = lane >> 4;
    const int kc = (lk ^ ((lr >> 1) & 3)) * 8;   // swizzled chunk offset (halves)
    f32x4 acc[8][4];
    #pragma unroll
    for (int m = 0; m < 8; ++m)
        #pragma unroll
        for (int n = 0; n < 4; ++n) acc[m][n] = (f32x4){0.f, 0.f, 0.f, 0.f};

    auto stage = [&](int slot, int kt) {
        #pragma unroll
        for (int r = 0; r < 2; ++r) {       // A: 256 rows x 32 cols, 2 loads/thread
            int id = r * 512 + t;
            int row = id >> 2, c = id & 3;
            int cg = c ^ ((row >> 1) & 3);
            GLOAD_LDS16(&A[(size_t)(mBase + row) * K + kt * 32 + cg * 8],
                        &As[slot][(size_t)(r * 512 + w * 64) * 8]);
        }
        #pragma unroll
        for (int r = 0; r < 2; ++r) {       // B: 256 rows x 32 cols, 2 loads/thread
            int id = r * 512 + t;
            int row = id >> 2, c = id & 3;
            int cg = c ^ ((row >> 1) & 3);
            GLOAD_LDS16(&BT[(size_t)(nBase + row) * K + kt * 32 + cg * 8],
                        &Bs[slot][(size_t)(r * 512 + w * 64) * 8]);
        }
    };
    auto compute = [&](int slot) {
        f16x8 af[8], bf[4];
        #pragma unroll
        for (int m = 0; m < 8; ++m)
            af[m] = *(const f16x8*)&As[slot][(wm * 128 + m * 16 + lr) * 32 + kc];
        #pragma unroll
        for (int n = 0; n < 4; ++n)
            bf[n] = *(const f16x8*)&Bs[slot][(wn * 64 + n * 16 + lr) * 32 + kc];
        #pragma unroll
        for (int m = 0; m < 8; ++m)
            #pragma unroll
            for (int n = 0; n < 4; ++n)
                acc[m][n] = __builtin_amdgcn_mfma_f32_16x16x32_f16(bf[n], af[m], acc[m][n], 0, 0, 0);
    };

    stage(0, 0);
    asm volatile("" ::: "memory");          // compiler fences: keep DMA issue order = age order
    stage(1, 1);
    asm volatile("" ::: "memory");
    stage(2, 2);
    asm volatile("" ::: "memory");
    for (int kt = 0; kt < NKT; ++kt) {
        if (kt < NKT - 2) {
            asm volatile("s_waitcnt vmcnt(8)" ::: "memory");   // stage(kt) landed; kt+1,kt+2 fly
        } else if (kt == NKT - 2) {
            asm volatile("s_waitcnt vmcnt(4)" ::: "memory");   // only stage(kt+1) still flying
        } else {
            asm volatile("s_waitcnt vmcnt(0)" ::: "memory");
        }
        __builtin_amdgcn_s_barrier();
        if (kt + 3 < NKT) stage((kt + 3) & 3, kt + 3);
        compute(kt & 3);
    }

    #pragma unroll
    for (int m = 0; m < 8; ++m) {
        int row = mBase + wm * 128 + m * 16 + lr;
        #pragma unroll
        for (int n = 0; n < 4; ++n) {
            int col = nBase + wn * 64 + n * 16 + lk * 4;
            f16x4 hv = { (f16)acc[m][n][0], (f16)acc[m][n][1],
                         (f16)acc[m][n][2], (f16)acc[m][n][3] };
            *(f16x4*)&Cout[(size_t)row * BNTOT + col] = hv;
        }
    }
}

// ---------------- f16 MFMA GEMM (proven): C[M x BNTOT] = A[M x 512] @ BT[BNTOT x 512]^T ----------------
// Kept for the output projection (scatter epilogue). Tile 128x256, BK=32, 8 waves,
// 3-buffer rotation, one barrier per K-step, counted vmcnt(3), T2 swizzle, T1 XCD swizzle.
template<int BNTOT, bool OUT_F32, int NY>
__global__ __launch_bounds__(512, 4) void gemm_k512(const f16* __restrict__ A, const f16* __restrict__ BT,
                                                    void* __restrict__ Cout, const float* __restrict__ bias,
                                                    const int* __restrict__ scatterIdx) {
    constexpr int K = 512;
    constexpr int NKT = K / 32;             // 16 K-tiles
    __shared__ f16 As[3][128 * 32];         // 3 x 8 KB
    __shared__ f16 Bs[3][256 * 32];         // 3 x 16 KB  (72 KB total -> 2 blocks/CU)
    const int t = threadIdx.x;
    const int orig = blockIdx.x + gridDim.x * blockIdx.y;
    constexpr int NWG = 256 * NY;           // gridDim.x == 256 (N_TOK/128)
    constexpr int CPX = NWG / 8;
    const int lin = (orig & 7) * CPX + (orig >> 3);
    const int mBase = (lin / NY) * 128;
    const int nBase = (lin % NY) * 256;
    const int w = t >> 6, lane = t & 63;
    const int wm = w >> 2, wn = w & 3;      // 2 x 4 wave grid
    const int lr = lane & 15, lk = lane >> 4;
    const int kc = (lk ^ ((lr >> 1) & 3)) * 8;   // swizzled chunk offset (halves)
    f32x4 acc[4][4];
    #pragma unroll
    for (int m = 0; m < 4; ++m)
        #pragma unroll
        for (int n = 0; n < 4; ++n) acc[m][n] = (f32x4){0.f, 0.f, 0.f, 0.f};

    auto stage = [&](int buf, int kt) {
        {
            int id = t;
            int row = id >> 2, c = id & 3;
            int cg = c ^ ((row >> 1) & 3);
            GLOAD_LDS16(&A[(size_t)(mBase + row) * K + kt * 32 + cg * 8],
                        &As[buf][(size_t)(w * 64) * 8]);
        }
        #pragma unroll
        for (int r = 0; r < 2; ++r) {
            int id = r * 512 + t;
            int row = id >> 2, c = id & 3;
            int cg = c ^ ((row >> 1) & 3);
            GLOAD_LDS16(&BT[(size_t)(nBase + row) * K + kt * 32 + cg * 8],
                        &Bs[buf][(size_t)(r * 512 + w * 64) * 8]);
        }
    };
    auto compute = [&](int buf) {
        f16x8 af[4], bf[4];
        #pragma unroll
        for (int m = 0; m < 4; ++m)
            af[m] = *(const f16x8*)&As[buf][(wm * 64 + m * 16 + lr) * 32 + kc];
        #pragma unroll
        for (int n = 0; n < 4; ++n)
            bf[n] = *(const f16x8*)&Bs[buf][(wn * 64 + n * 16 + lr) * 32 + kc];
        #pragma unroll
        for (int m = 0; m < 4; ++m)
            #pragma unroll
            for (int n = 0; n < 4; ++n)
                acc[m][n] = __builtin_amdgcn_mfma_f32_16x16x32_f16(bf[n], af[m], acc[m][n], 0, 0, 0);
    };

    stage(0, 0);
    asm volatile("" ::: "memory");          // compiler fence: keep stage(0) DMAs oldest
    stage(1, 1);
    for (int kt = 0; kt < NKT; ++kt) {
        if (kt < NKT - 1) {
            asm volatile("s_waitcnt vmcnt(3)" ::: "memory");
        } else {
            asm volatile("s_waitcnt vmcnt(0)" ::: "memory");
        }
        __builtin_amdgcn_s_barrier();
        if (kt + 2 < NKT) stage((kt + 2) % 3, kt + 2);
        compute(kt % 3);
    }

    #pragma unroll
    for (int m = 0; m < 4; ++m) {
        int row = mBase + wm * 64 + m * 16 + lr;
        int srow = OUT_F32 ? scatterIdx[row] : row;
        #pragma unroll
        for (int n = 0; n < 4; ++n) {
            int col = nBase + wn * 64 + n * 16 + lk * 4;
            if constexpr (OUT_F32) {
                float4 bv = *(const float4*)&bias[col];
                float4 sv = make_float4(acc[m][n][0] + bv.x, acc[m][n][1] + bv.y,
                                        acc[m][n][2] + bv.z, acc[m][n][3] + bv.w);
                *(float4*)&((float*)Cout)[(size_t)srow * BNTOT + col] = sv;
            } else {
                f16x4 hv = { (f16)acc[m][n][0], (f16)acc[m][n][1],
                             (f16)acc[m][n][2], (f16)acc[m][n][3] };
                *(f16x4*)&((f16*)Cout)[(size_t)srow * BNTOT + col] = hv;
            }
        }
    }
}

// ---------------- segment-sum partials: grid (NL, 4), deterministic scratch ----------------
__global__ __launch_bounds__(256) void pool_part_k(const f16* __restrict__ qkvh,
                                                   const int* __restrict__ baseG,
                                                   const int* __restrict__ counts,
                                                   float* __restrict__ psum) {
    int l = blockIdx.x, g = blockIdx.y;
    int t = threadIdx.x;
    int c = t & 127, rg = t >> 7;
    int b0 = baseG[l];
    int cnt = counts[l];
    f32x4 a0 = {0.f,0.f,0.f,0.f}, a1 = {0.f,0.f,0.f,0.f};
    for (int p = g * 2 + rg; p < cnt; p += 8) {
        f16x8 v = *(const f16x8*)&qkvh[(size_t)(b0 + p) * QKVC + c * 8];
        a0[0] += (float)v[0]; a0[1] += (float)v[1]; a0[2] += (float)v[2]; a0[3] += (float)v[3];
        a1[0] += (float)v[4]; a1[1] += (float)v[5]; a1[2] += (float)v[6]; a1[3] += (float)v[7];
    }
    __shared__ f32x4 red[2][128][2];
    red[rg][c][0] = a0; red[rg][c][1] = a1;
    __syncthreads();
    if (t < 128) {
        f32x4 s0 = red[0][t][0] + red[1][t][0];
        f32x4 s1 = red[0][t][1] + red[1][t][1];
        size_t o = ((size_t)g * NL + l) * 1024 + t * 8;
        *(f32x4*)&psum[o] = s0;
        *(f32x4*)&psum[o + 4] = s1;
    }
}

// ---------------- pooling finalize: sum 4 partials, divide, emit f32 + f16 ----------------
__global__ __launch_bounds__(256) void pool_fin_k(const float* __restrict__ psum,
                                                  const int* __restrict__ counts,
                                                  float* __restrict__ ql, float* __restrict__ kl,
                                                  f16* __restrict__ qlh, f16* __restrict__ klh) {
    int l = blockIdx.x;
    int t = threadIdx.x;
    int bse = t * 4;
    float inv = 1.0f / (float)(counts[l] > 0 ? counts[l] : 1);
    f32x4 s = {0.f,0.f,0.f,0.f};
    #pragma unroll
    for (int g = 0; g < 4; ++g)
        s += *(const f32x4*)&psum[((size_t)g * NL + l) * 1024 + bse];
    s *= inv;
    f16x4 hv = { (f16)s[0], (f16)s[1], (f16)s[2], (f16)s[3] };
    if (bse < 512) {
        int h = bse >> 6, d0 = bse & 63;
        size_t o = ((size_t)(h * 64 + l)) * 64 + d0;
        *(f32x4*)&ql[o] = s;
        *(f16x4*)&qlh[o] = hv;
    } else {
        int bb = bse - 512;
        int h = bb >> 6, d0 = bb & 63;
        size_t o = ((size_t)(h * 64 + l)) * 64 + d0;
        *(f32x4*)&kl[o] = s;
        *(f16x4*)&klh[o] = hv;
    }
}

// ---------------- attn2 = softmax(ql@kl^T) rows; per-head row/col abs-sum maxes ----------------
__global__ __launch_bounds__(256) void attn2_k(const float* __restrict__ ql, const float* __restrict__ kl,
                                               float* __restrict__ a_out, float* __restrict__ mrow,
                                               float* __restrict__ mcol) {
    int h = blockIdx.x;
    __shared__ float qs[64][65], ks[64][65], a[64][65];
    __shared__ float red[64][4];
    __shared__ float rowv[64], colv[64];
    int t = threadIdx.x;
    for (int idx = t; idx < 4096; idx += 256) {
        int r = idx >> 6, c = idx & 63;
        qs[r][c] = ql[h * 4096 + idx];
        ks[r][c] = kl[h * 4096 + idx];
    }
    __syncthreads();
    int i = t >> 2, q4 = t & 3, j0 = q4 * 16;
    float o[16];
    #pragma unroll
    for (int jj = 0; jj < 16; ++jj) o[jj] = 0.f;
    for (int d = 0; d < 64; ++d) {
        float qv = qs[i][d];
        #pragma unroll
        for (int jj = 0; jj < 16; ++jj) o[jj] += qv * ks[j0 + jj][d];
    }
    float pmx = o[0];
    #pragma unroll
    for (int jj = 1; jj < 16; ++jj) pmx = fmaxf(pmx, o[jj]);
    red[i][q4] = pmx;
    __syncthreads();
    float rm = fmaxf(fmaxf(red[i][0], red[i][1]), fmaxf(red[i][2], red[i][3]));
    float psum = 0.f;
    #pragma unroll
    for (int jj = 0; jj < 16; ++jj) { o[jj] = expf(o[jj] - rm); psum += o[jj]; }
    __syncthreads();
    red[i][q4] = psum;
    __syncthreads();
    float rs = red[i][0] + red[i][1] + red[i][2] + red[i][3];
    float inv = 1.0f / rs;
    #pragma unroll
    for (int jj = 0; jj < 16; ++jj) { o[jj] *= inv; a[i][j0 + jj] = o[jj]; }
    __syncthreads();
    for (int idx = t; idx < 4096; idx += 256) a_out[h * 4096 + idx] = a[idx >> 6][idx & 63];
    float rsum = 0.f;
    #pragma unroll
    for (int jj = 0; jj < 16; ++jj) rsum += o[jj];
    __syncthreads();
    red[i][q4] = rsum;
    __syncthreads();
    if (q4 == 0) rowv[i] = red[i][0] + red[i][1] + red[i][2] + red[i][3];
    float csum = 0.f;
    #pragma unroll
    for (int jj = 0; jj < 16; ++jj) csum += a[j0 + jj][i];
    __syncthreads();
    red[i][q4] = csum;
    __syncthreads();
    if (q4 == 0) colv[i] = red[i][0] + red[i][1] + red[i][2] + red[i][3];
    __syncthreads();
    if (t == 0) {
        float mr = rowv[0], mc = colv[0];
        for (int j = 1; j < 64; ++j) { mr = fmaxf(mr, rowv[j]); mc = fmaxf(mc, colv[j]); }
        mrow[h] = mr; mcol[h] = mc;
    }
}

// ---------------- fused attn3 + pinv-NS (block x==0 = pinv; x=1..64 = attn3 chunks) ----------------
__global__ __launch_bounds__(256) void attn3_pinv_k(const f16* __restrict__ qkvh,
                                                    const f16* __restrict__ qlh,
                                                    float* __restrict__ pm, float* __restrict__ ps,
                                                    float* __restrict__ pacc,
                                                    const float* __restrict__ a_g,
                                                    const float* __restrict__ mrow,
                                                    const float* __restrict__ mcol,
                                                    float* __restrict__ zg) {
    union ShU {
        struct { f16 Qls[64 * 64]; f16 Ks[64 * 64]; f16 vT[64 * 72]; f16 Ps[64 * 72]; float fsh[64]; } a3;
        struct { f16 zRh[64][72], zRl[64][72], cRh[64][72], cRl[64][72],
                 Xh[64][72], Xl[64][72], Yh[64][72], Yl[64][72]; } pv;
    };
    __shared__ ShU sh;
    const int t = threadIdx.x;
    const int w = t >> 6, lane = t & 63;
    const int lr = lane & 15;
    const int h = blockIdx.y;

    if (blockIdx.x == 0) {
        const int lk = lane >> 4;
        f16 (&zRh)[64][72] = sh.pv.zRh; f16 (&zRl)[64][72] = sh.pv.zRl;
        f16 (&cRh)[64][72] = sh.pv.cRh; f16 (&cRl)[64][72] = sh.pv.cRl;
        f16 (&Xh)[64][72]  = sh.pv.Xh;  f16 (&Xl)[64][72]  = sh.pv.Xl;
        f16 (&Yh)[64][72]  = sh.pv.Yh;  f16 (&Yl)[64][72]  = sh.pv.Yl;
        float mr = mrow[0], mc = mcol[0];
        #pragma unroll
        for (int k = 1; k < 8; ++k) { mr = fmaxf(mr, mrow[k]); mc = fmaxf(mc, mcol[k]); }
        const float inv0 = 1.0f / (mr * mc);
        for (int idx = t; idx < 4096; idx += 256) {
            int r = idx >> 6, c = idx & 63;
            float zv = a_g[h * 4096 + idx] * inv0;
            f16 hv = (f16)zv;
            zRh[c][r] = hv; zRl[c][r] = (f16)(zv - (float)hv);
        }
        __syncthreads();

        f32x4 po[4];
        auto product = [&](const f16 (*Lh)[72], const f16 (*Ll)[72],
                           const f16 (*Rh)[72], const f16 (*Rl)[72]) {
            #pragma unroll
            for (int n = 0; n < 4; ++n) po[n] = (f32x4){0.f, 0.f, 0.f, 0.f};
            #pragma unroll
            for (int ck = 0; ck < 2; ++ck) {
                f16x8 axh = *(const f16x8*)&Lh[w * 16 + lr][ck * 32 + lk * 8];
                f16x8 axl = *(const f16x8*)&Ll[w * 16 + lr][ck * 32 + lk * 8];
                #pragma unroll
                for (int n = 0; n < 4; ++n) {
                    f16x8 byh = *(const f16x8*)&Rh[n * 16 + lr][ck * 32 + lk * 8];
                    f16x8 byl = *(const f16x8*)&Rl[n * 16 + lr][ck * 32 + lk * 8];
                    po[n] = __builtin_amdgcn_mfma_f32_16x16x32_f16(byh, axh, po[n], 0, 0, 0);
                    po[n] = __builtin_amdgcn_mfma_f32_16x16x32_f16(byl, axh, po[n], 0, 0, 0);
                    po[n] = __builtin_amdgcn_mfma_f32_16x16x32_f16(byh, axl, po[n], 0, 0, 0);
                }
            }
        };

        for (int it = 0; it < 6; ++it) {
            for (int idx = t; idx < 4096; idx += 256) {
                int r = idx >> 6, c = idx & 63;
                float av = a_g[h * 4096 + idx];
                f16 ah = (f16)av;
                Xh[r][c] = ah; Xl[r][c] = (f16)(av - (float)ah);
                float zv = (float)zRh[r][c] + (float)zRl[r][c];
                f16 zh = (f16)zv;
                Yh[c][r] = zh; Yl[c][r] = (f16)(zv - (float)zh);
            }
            __syncthreads();
            product(Xh, Xl, Yh, Yl);                       // C = a @ z
            __syncthreads();
            #pragma unroll
            for (int n = 0; n < 4; ++n)
                #pragma unroll
                for (int j = 0; j < 4; ++j) {
                    int r = w * 16 + lr, c = n * 16 + lk * 4 + j;
                    float v = po[n][j]; f16 hv = (f16)v; f16 lv = (f16)(v - (float)hv);
                    cRh[r][c] = hv; cRl[r][c] = lv;
                    Xh[c][r] = hv;  Xl[c][r] = lv;
                }
            __syncthreads();
            product(cRh, cRl, Xh, Xl);                     // C @ C
            #pragma unroll
            for (int n = 0; n < 4; ++n)
                #pragma unroll
                for (int j = 0; j < 4; ++j) {
                    int r = w * 16 + lr, c = n * 16 + lk * 4 + j;
                    float v = 7.f * ((float)cRh[r][c] + (float)cRl[r][c]) - po[n][j];
                    f16 hv = (f16)v;
                    Yh[c][r] = hv; Yl[c][r] = (f16)(v - (float)hv);
                }
            __syncthreads();
            product(cRh, cRl, Yh, Yl);                     // C @ D
            #pragma unroll
            for (int n = 0; n < 4; ++n)
                #pragma unroll
                for (int j = 0; j < 4; ++j) {
                    int r = w * 16 + lr, c = n * 16 + lk * 4 + j;
                    float v = 15.f * ((float)cRh[r][c] + (float)cRl[r][c]) - po[n][j];
                    f16 hv = (f16)v;
                    Xh[c][r] = hv; Xl[c][r] = (f16)(v - (float)hv);
                }
            __syncthreads();
            product(zRh, zRl, Xh, Xl);                     // z @ E
            #pragma unroll
            for (int n = 0; n < 4; ++n)
                #pragma unroll
                for (int j = 0; j < 4; ++j) {
                    int r = w * 16 + lr, c = n * 16 + lk * 4 + j;
                    float v = 0.25f * (13.f * ((float)zRh[r][c] + (float)zRl[r][c]) - po[n][j]);
                    f16 hv = (f16)v;
                    zRh[r][c] = hv; zRl[r][c] = (f16)(v - (float)hv);
                }
            __syncthreads();
        }
        for (int idx = t; idx < 4096; idx += 256) {
            int r = idx >> 6, c = idx & 63;
            zg[h * 4096 + idx] = (float)zRh[r][c] + (float)zRl[r][c];
        }
        return;
    }

    // ---------------- attn3 flash path ----------------
    const int cx = blockIdx.x - 1;
    const int hi = lane >> 4;
    f16* Qls = sh.a3.Qls;
    f16* Ks  = sh.a3.Ks;
    f16* vT  = sh.a3.vT;
    f16* Ps  = sh.a3.Ps;
    float* fsh = sh.a3.fsh;

    #pragma unroll
    for (int pss = 0; pss < 2; ++pss) {
        int q = pss * 256 + t;
        int r = q >> 3, cs = (q & 7) ^ (r & 7);
        GLOAD_LDS16(&qlh[(size_t)h * 4096 + r * 64 + cs * 8], &Qls[(size_t)(pss * 256 + w * 64) * 8]);
    }
    float m_reg = -1e30f, s_reg = 0.f;
    f32x4 accT[4];
    #pragma unroll
    for (int lf = 0; lf < 4; ++lf) accT[lf] = (f32x4){0.f, 0.f, 0.f, 0.f};

    const int vk8 = t & 7, vnn = t >> 3;

    for (int sub = 0; sub < 8; ++sub) {
        const int n0 = cx * 512 + sub * 64;
        __syncthreads();
        #pragma unroll
        for (int pss = 0; pss < 2; ++pss) {
            int q = pss * 256 + t;
            int r = q >> 3, cs = (q & 7) ^ (r & 7);
            GLOAD_LDS16(&qkvh[(size_t)(n0 + r) * QKVC + 512 + h * 64 + cs * 8],
                        &Ks[(size_t)(pss * 256 + w * 64) * 8]);
        }
        #pragma unroll
        for (int p2 = 0; p2 < 2; ++p2) {
            int n = vnn + 32 * p2;
            f16x8 rv = *(const f16x8*)&qkvh[(size_t)(n0 + n) * QKVC + 1024 + h * 64 + vk8 * 8];
            #pragma unroll
            for (int i = 0; i < 8; ++i) {
                int e = i ^ vk8;
                vT[(vk8 * 8 + e) * 72 + n] = rv[e];
            }
        }
        __syncthreads();
        f32x4 c[4];
        #pragma unroll
        for (int kf = 0; kf < 4; ++kf) c[kf] = (f32x4){0.f, 0.f, 0.f, 0.f};
        const int lq = w * 16 + lr;
        #pragma unroll
        for (int ks = 0; ks < 2; ++ks) {
            f16x8 bf = *(const f16x8*)&Qls[lq * 64 + (((ks * 4 + hi) ^ (lq & 7)) * 8)];
            #pragma unroll
            for (int kf = 0; kf < 4; ++kf) {
                int rn = kf * 16 + lr;
                f16x8 af = *(const f16x8*)&Ks[rn * 64 + (((ks * 4 + hi) ^ (rn & 7)) * 8)];
                c[kf] = __builtin_amdgcn_mfma_f32_16x16x32_f16(af, bf, c[kf], 0, 0, 0);
            }
        }
        float tmax = -1e30f;
        #pragma unroll
        for (int kf = 0; kf < 4; ++kf)
            #pragma unroll
            for (int j = 0; j < 4; ++j) tmax = fmaxf(tmax, c[kf][j]);
        tmax = fmaxf(tmax, __shfl_xor(tmax, 16));
        tmax = fmaxf(tmax, __shfl_xor(tmax, 32));
        float newm = fmaxf(m_reg, tmax);
        float fct = __expf(m_reg - newm);
        float psum = 0.f;
        #pragma unroll
        for (int kf = 0; kf < 4; ++kf) {
            f16x4 pk;
            #pragma unroll
            for (int j = 0; j < 4; ++j) {
                float e = __expf(c[kf][j] - newm);
                psum += e;
                pk[j] = (f16)e;
            }
            *(f16x4*)&Ps[lq * 72 + kf * 16 + hi * 4] = pk;
        }
        psum += __shfl_xor(psum, 16);
        psum += __shfl_xor(psum, 32);
        s_reg = s_reg * fct + psum;
        m_reg = newm;
        if (hi == 0) fsh[lq] = fct;
        __syncthreads();
        #pragma unroll
        for (int lf = 0; lf < 4; ++lf) {
            f32x4 fr = *(const f32x4*)&fsh[lf * 16 + hi * 4];
            accT[lf] *= fr;
        }
        #pragma unroll
        for (int ks = 0; ks < 2; ++ks) {
            f16x8 bf = *(const f16x8*)&vT[(w * 16 + lr) * 72 + ks * 32 + hi * 8];
            #pragma unroll
            for (int lf = 0; lf < 4; ++lf) {
                f16x8 af = *(const f16x8*)&Ps[(lf * 16 + lr) * 72 + ks * 32 + hi * 8];
                accT[lf] = __builtin_amdgcn_mfma_f32_16x16x32_f16(af, bf, accT[lf], 0, 0, 0);
            }
        }
    }
    int part = h * NCHUNK + cx;
    if (hi == 0) {
        pm[part * 64 + w * 16 + lr] = m_reg;
        ps[part * 64 + w * 16 + lr] = s_reg;
    }
    #pragma unroll
    for (int lf = 0; lf < 4; ++lf)
        #pragma unroll
        for (int j = 0; j < 4; ++j)
            pacc[((size_t)part * 64 + (lf * 16 + hi * 4 + j)) * 64 + (w * 16 + lr)] = accT[lf][j];
}

// ---------------- merge attn3 partials -> T[h][l][d] ----------------
__global__ void attn3_merge_k(const float* __restrict__ pm, const float* __restrict__ ps,
                              const float* __restrict__ pacc, float* __restrict__ T) {
    int l = blockIdx.x, h = blockIdx.y, d = threadIdx.x;
    float m = -1e30f;
    for (int c = 0; c < NCHUNK; ++c) m = fmaxf(m, pm[(h * NCHUNK + c) * 64 + l]);
    float s = 0.f, a = 0.f;
    for (int c = 0; c < NCHUNK; ++c) {
        float wgt = __expf(pm[(h * NCHUNK + c) * 64 + l] - m);
        s += ps[(h * NCHUNK + c) * 64 + l] * wgt;
        a += pacc[((size_t)(h * NCHUNK + c) * 64 + l) * 64 + d] * wgt;
    }
    T[(h * 64 + l) * 64 + d] = a / s;
}

// ---------------- final product M = z @ T (hi/lo MFMA), emit M^T hi/lo f16 ----------------
__global__ __launch_bounds__(256) void zmatT_fin_k(const float* __restrict__ zg,
                                                   const float* __restrict__ T,
                                                   f16* __restrict__ MthHi, f16* __restrict__ MthLo) {
    const int h = blockIdx.x;
    __shared__ f16 zFh[64][72], zFl[64][72], tCh[64][72], tCl[64][72];
    const int t = threadIdx.x;
    const int w = t >> 6, lane = t & 63;
    const int lr = lane & 15, lk = lane >> 4;
    for (int idx = t; idx < 4096; idx += 256) {
        int r = idx >> 6, c = idx & 63;
        float zv = zg[h * 4096 + idx]; f16 zh = (f16)zv;
        zFh[r][c] = zh; zFl[r][c] = (f16)(zv - (float)zh);
        float tv = T[h * 4096 + idx]; f16 th = (f16)tv;
        tCh[c][r] = th; tCl[c][r] = (f16)(tv - (float)th);
    }
    __syncthreads();
    f32x4 po[4];
    #pragma unroll
    for (int n = 0; n < 4; ++n) po[n] = (f32x4){0.f, 0.f, 0.f, 0.f};
    #pragma unroll
    for (int ck = 0; ck < 2; ++ck) {
        f16x8 axh = *(const f16x8*)&zFh[w * 16 + lr][ck * 32 + lk * 8];
        f16x8 axl = *(const f16x8*)&zFl[w * 16 + lr][ck * 32 + lk * 8];
        #pragma unroll
        for (int n = 0; n < 4; ++n) {
            f16x8 byh = *(const f16x8*)&tCh[n * 16 + lr][ck * 32 + lk * 8];
            f16x8 byl = *(const f16x8*)&tCl[n * 16 + lr][ck * 32 + lk * 8];
            po[n] = __builtin_amdgcn_mfma_f32_16x16x32_f16(byh, axh, po[n], 0, 0, 0);
            po[n] = __builtin_amdgcn_mfma_f32_16x16x32_f16(byl, axh, po[n], 0, 0, 0);
            po[n] = __builtin_amdgcn_mfma_f32_16x16x32_f16(byh, axl, po[n], 0, 0, 0);
        }
    }
    #pragma unroll
    for (int n = 0; n < 4; ++n)
        #pragma unroll
        for (int j = 0; j < 4; ++j) {
            int r = w * 16 + lr, c = n * 16 + lk * 4 + j;
            float v = po[n][j]; f16 hv = (f16)v;
            MthHi[h * 4096 + c * 64 + r] = hv;             // transposed layout [h][d][l]
            MthLo[h * 4096 + c * 64 + r] = (f16)(v - (float)hv);
        }
}

// ---------------- fused attn1 + depthwise conv: softmax(Q@kl^T)@M + conv(v) -> Yh ----------------
__global__ __launch_bounds__(256) void attn1_k(const f16* __restrict__ qkvh, const f16* __restrict__ klh,
                                               const f16* __restrict__ MthHi, const f16* __restrict__ MthLo,
                                               const float* __restrict__ resk, f16* __restrict__ Yh) {
    const int h = blockIdx.y;
    const int p0 = blockIdx.x * 128;
    const int t = threadIdx.x;
    const int w = t >> 6, lane = t & 63;
    const int lr = lane & 15, hi = lane >> 4;
    __shared__ f16 QPs[128][72];     // Q tile -> P tile -> O tile (wave-private rows)
    __shared__ f16 Ks[64][72];
    __shared__ f16 Mhi[64][72];
    __shared__ f16 Mlo[64][72];
    __shared__ f16 vt[160][72];      // v rows [p0-16, p0+144)

    #pragma unroll
    for (int i = 0; i < 4; ++i) {
        int id = i * 256 + t, row = id >> 3, c8 = id & 7;
        *(f16x8*)&QPs[row][c8 * 8] = *(const f16x8*)&qkvh[(size_t)(p0 + row) * QKVC + h * 64 + c8 * 8];
    }
    #pragma unroll
    for (int i = 0; i < 2; ++i) {
        int id = i * 256 + t, row = id >> 3, c8 = id & 7;
        *(f16x8*)&Ks[row][c8 * 8]  = *(const f16x8*)&klh[h * 4096 + id * 8];
        *(f16x8*)&Mhi[row][c8 * 8] = *(const f16x8*)&MthHi[h * 4096 + id * 8];
        *(f16x8*)&Mlo[row][c8 * 8] = *(const f16x8*)&MthLo[h * 4096 + id * 8];
    }
    for (int id = t; id < 160 * 8; id += 256) {
        int rr = id >> 3, c8 = id & 7;
        int pg = p0 - 16 + rr;
        int4 v = {0, 0, 0, 0};
        if (pg >= 0 && pg < N_TOK)
            v = *(const int4*)&qkvh[(size_t)pg * QKVC + 1024 + h * 64 + c8 * 8];
        *(int4*)&vt[rr][c8 * 8] = v;
    }
    float wk[KSZ];
    #pragma unroll
    for (int k = 0; k < KSZ; ++k) wk[k] = resk[h * KSZ + k];
    __syncthreads();

    f32x4 c[4][2];
    #pragma unroll
    for (int lf = 0; lf < 4; ++lf)
        #pragma unroll
        for (int nf = 0; nf < 2; ++nf) c[lf][nf] = (f32x4){0.f, 0.f, 0.f, 0.f};
    #pragma unroll
    for (int ks = 0; ks < 2; ++ks) {
        f16x8 af[4], bf[2];
        #pragma unroll
        for (int lf = 0; lf < 4; ++lf) af[lf] = *(const f16x8*)&Ks[lf * 16 + lr][ks * 32 + hi * 8];
        #pragma unroll
        for (int nf = 0; nf < 2; ++nf) bf[nf] = *(const f16x8*)&QPs[w * 32 + nf * 16 + lr][ks * 32 + hi * 8];
        #pragma unroll
        for (int lf = 0; lf < 4; ++lf)
            #pragma unroll
            for (int nf = 0; nf < 2; ++nf)
                c[lf][nf] = __builtin_amdgcn_mfma_f32_16x16x32_f16(af[lf], bf[nf], c[lf][nf], 0, 0, 0);
    }

    #pragma unroll
    for (int nf = 0; nf < 2; ++nf) {
        float m = -1e30f;
        #pragma unroll
        for (int lf = 0; lf < 4; ++lf)
            #pragma unroll
            for (int j = 0; j < 4; ++j) m = fmaxf(m, c[lf][nf][j]);
        m = fmaxf(m, __shfl_xor(m, 16));
        m = fmaxf(m, __shfl_xor(m, 32));
        float s = 0.f;
        #pragma unroll
        for (int lf = 0; lf < 4; ++lf)
            #pragma unroll
            for (int j = 0; j < 4; ++j) { float e = __expf(c[lf][nf][j] - m); c[lf][nf][j] = e; s += e; }
        s += __shfl_xor(s, 16);
        s += __shfl_xor(s, 32);
        float inv = 1.0f / s;
        #pragma unroll
        for (int lf = 0; lf < 4; ++lf) {
            f16x4 pk;
            #pragma unroll
            for (int j = 0; j < 4; ++j) pk[j] = (f16)(c[lf][nf][j] * inv);
            *(f16x4*)&QPs[w * 32 + nf * 16 + lr][lf * 16 + hi * 4] = pk;
        }
    }

    f32x4 o[2][4];
    #pragma unroll
    for (int nf = 0; nf < 2; ++nf)
        #pragma unroll
        for (int df = 0; df < 4; ++df) o[nf][df] = (f32x4){0.f, 0.f, 0.f, 0.f};
    #pragma unroll
    for (int ks = 0; ks < 2; ++ks) {
        f16x8 pa[2], bh[4], bl[4];
        #pragma unroll
        for (int nf = 0; nf < 2; ++nf) pa[nf] = *(const f16x8*)&QPs[w * 32 + nf * 16 + lr][ks * 32 + hi * 8];
        #pragma unroll
        for (int df = 0; df < 4; ++df) {
            bh[df] = *(const f16x8*)&Mhi[df * 16 + lr][ks * 32 + hi * 8];
            bl[df] = *(const f16x8*)&Mlo[df * 16 + lr][ks * 32 + hi * 8];
        }
        #pragma unroll
        for (int nf = 0; nf < 2; ++nf)
            #pragma unroll
            for (int df = 0; df < 4; ++df) {
                o[nf][df] = __builtin_amdgcn_mfma_f32_16x16x32_f16(pa[nf], bh[df], o[nf][df], 0, 0, 0);
                o[nf][df] = __builtin_amdgcn_mfma_f32_16x16x32_f16(pa[nf], bl[df], o[nf][df], 0, 0, 0);
            }
    }

    #pragma unroll
    for (int nf = 0; nf < 2; ++nf)
        #pragma unroll
        for (int df = 0; df < 4; ++df)
            #pragma unroll
            for (int j = 0; j < 4; ++j)
                QPs[w * 32 + nf * 16 + hi * 4 + j][df * 16 + lr] = (f16)(o[nf][df][j]);
    __syncthreads();

    // vectorized conv + combine: thread owns a column PAIR (f16x2 reads, half the LDS instrs)
    const int d2 = t & 31, rg8 = t >> 5;
    const int r0 = rg8 * 16;
    float c0[48], c1[48];
    #pragma unroll
    for (int j = 0; j < 48; ++j) {
        f16x2 v = *(const f16x2*)&vt[r0 + j][d2 * 2];
        c0[j] = (float)v[0]; c1[j] = (float)v[1];
    }
    #pragma unroll
    for (int pp = 0; pp < 16; ++pp) {
        float a0 = 0.f, a1 = 0.f;
        #pragma unroll
        for (int k = 0; k < KSZ; ++k) { a0 += wk[k] * c0[pp + k]; a1 += wk[k] * c1[pp + k]; }
        int row = r0 + pp;
        f16x2 qv = *(const f16x2*)&QPs[row][d2 * 2];
        f16x2 ov;
        ov[0] = (f16)(a0 + (float)qv[0]);
        ov[1] = (f16)(a1 + (float)qv[1]);
        *(f16x2*)&Yh[(size_t)(p0 + row) * 512 + h * 64 + d2 * 2] = ov;
    }
}

// ---------------- host launch ----------------
extern "C" void kernel_launch(void* const* d_in, const int* in_sizes, int n_in,
                              void* d_out, int out_size, void* d_ws, size_t ws_size,
                              hipStream_t stream) {
    const float* x    = (const float*)d_in[0];
    const float* Wqkv = (const float*)d_in[1];
    const float* Wout = (const float*)d_in[2];
    const float* bout = (const float*)d_in[3];
    const float* resk = (const float*)d_in[4];
    const int*   labels = (const int*)d_in[5];
    float* out = (float*)d_out;

    char* w = (char*)d_ws;
    size_t off = 0;
    auto alloc = [&](size_t bytes) {
        void* p = w + off;
        off += (bytes + 255) & ~(size_t)255;
        return p;
    };
    f16* xh     = (f16*)alloc((size_t)N_TOK * DIMC * 2);       // sorted
    f16* qkvh   = (f16*)alloc((size_t)N_TOK * QKVC * 2);       // sorted
    f16* WqkvT  = (f16*)alloc((size_t)QKVC * DIMC * 2);
    f16* WoutT  = (f16*)alloc((size_t)DIMC * DIMC * 2);
    f16* Yh     = (f16*)alloc((size_t)N_TOK * DIMC * 2);       // sorted
    int* counts = (int*)alloc(NL * 4);
    int* chunkCnt = (int*)alloc((size_t)128 * NL * 4);
    int* baseC  = (int*)alloc((size_t)128 * NL * 4);
    int* baseG  = (int*)alloc(NL * 4);
    int* indexA = (int*)alloc((size_t)N_TOK * 4);
    float* ql   = (float*)alloc((size_t)NH * 64 * 64 * 4);
    float* kl   = (float*)alloc((size_t)NH * 64 * 64 * 4);
    f16* qlh    = (f16*)alloc((size_t)NH * 64 * 64 * 2);
    f16* klh    = (f16*)alloc((size_t)NH * 64 * 64 * 2);
    float* a2   = (float*)alloc((size_t)NH * 64 * 64 * 4);
    float* mrow = (float*)alloc(NH * 4);
    float* mcol = (float*)alloc(NH * 4);
    float* Tb   = (float*)alloc((size_t)NH * 64 * 64 * 4);
    float* zg   = (float*)alloc((size_t)NH * 64 * 64 * 4);
    f16* MthHi  = (f16*)alloc((size_t)NH * 64 * 64 * 2);
    f16* MthLo  = (f16*)alloc((size_t)NH * 64 * 64 * 2);
    float* pm   = (float*)alloc((size_t)NH * NCHUNK * 64 * 4);
    float* ps   = (float*)alloc((size_t)NH * NCHUNK * 64 * 4);
    float* pacc = (float*)alloc((size_t)NH * NCHUNK * 64 * 64 * 4);
    float* psum = (float*)alloc((size_t)4 * NL * 1024 * 4);    // 1 MB pooling partials

    hipMemsetAsync(counts, 0, NL * 4, stream);

    // parallel stable counting sort: chunk hist -> scan -> parallel placement
    hist_chunk_k<<<128, 256, 0, stream>>>(labels, counts, chunkCnt);
    scan_all_k<<<1, 64, 0, stream>>>(chunkCnt, counts, baseC, baseG);
    place_k<<<128, 256, 0, stream>>>(labels, baseC, indexA);
    // gather+convert x rows into sorted order
    gather_cvt_k<<<N_TOK / 2, 256, 0, stream>>>((const float4*)x, indexA, (f16x4*)xh);
    // weight transposes
    transpose_k<<<dim3(QKVC / 32, DIMC / 32), dim3(32, 8), 0, stream>>>(Wqkv, WqkvT, DIMC, QKVC);
    transpose_k<<<dim3(DIMC / 32, DIMC / 32), dim3(32, 8), 0, stream>>>(Wout, WoutT, DIMC, DIMC);
    // qkv = x_sorted @ Wqkv  (sorted domain) -- NEW 256x256 deep-pipeline kernel
    gemm256_k512<QKVC, 6><<<dim3(N_TOK / 256, QKVC / 256), 512, 0, stream>>>(xh, WqkvT, qkvh);
    // segment pooling: 4-way partials (256 blocks) + finalize
    pool_part_k<<<dim3(NL, 4), 256, 0, stream>>>(qkvh, baseG, counts, psum);
    pool_fin_k<<<NL, 256, 0, stream>>>(psum, counts, ql, kl, qlh, klh);
    // attn2 (produces a2, mrow, mcol for pinv)
    attn2_k<<<NH, 256, 0, stream>>>(ql, kl, a2, mrow, mcol);
    // fused: attn3 flash chunks (x=1..64) + pinv NS iterations (x=0)
    attn3_pinv_k<<<dim3(NCHUNK + 1, NH), 256, 0, stream>>>(qkvh, qlh, pm, ps, pacc, a2, mrow, mcol, zg);
    attn3_merge_k<<<dim3(NL, NH), 64, 0, stream>>>(pm, ps, pacc, Tb);
    // final M^T = (z@T)^T in hi/lo f16
    zmatT_fin_k<<<NH, 256, 0, stream>>>(zg, Tb, MthHi, MthLo);
    // fused attn1 + depthwise conv -> Yh (sorted)
    attn1_k<<<dim3(N_TOK / 128, NH), 256, 0, stream>>>(qkvh, klh, MthHi, MthLo, resk, Yh);
    // final projection + bias, scatter rows back to original order (proven kernel)
    gemm_k512<DIMC, true, 2><<<dim3(N_TOK / 128, DIMC / 256), 512, 0, stream>>>(Yh, WoutT, out, bout, indexA);
}

// Round 23
// 297.325 us; speedup vs baseline: 1.0557x; 1.0557x over previous
//
#include <hip/hip_runtime.h>
#include <hip/hip_bf16.h>

// ---------------- problem constants ----------------
#define N_TOK 32768
#define DIMC  512
#define NH    8
#define DHD   64
#define NL    64
#define KSZ   33
#define QKVC  1536
#define NCHUNK 64   // attn3 chunks; 512 tokens per block

typedef _Float16 f16;
typedef _Float16 f16x8 __attribute__((ext_vector_type(8)));
typedef _Float16 f16x4 __attribute__((ext_vector_type(4)));
typedef _Float16 f16x2 __attribute__((ext_vector_type(2)));
typedef float    f32x4 __attribute__((ext_vector_type(4)));

#define GLOAD_LDS16(gp, lp) \
    __builtin_amdgcn_global_load_lds((const __attribute__((address_space(1))) void*)(gp), \
                                     (__attribute__((address_space(3))) void*)(lp), 16, 0, 0)

// ---------------- transpose f32 (R x C) -> f16 (C x R) ----------------
__global__ void transpose_k(const float* __restrict__ W, f16* __restrict__ WT, int R, int C) {
    __shared__ float tile[32][33];
    int bx = blockIdx.x * 32, by = blockIdx.y * 32;
    int tx = threadIdx.x, ty = threadIdx.y;
    #pragma unroll
    for (int i = 0; i < 32; i += 8)
        tile[ty + i][tx] = W[(size_t)(by + ty + i) * C + bx + tx];
    __syncthreads();
    #pragma unroll
    for (int i = 0; i < 32; i += 8)
        WT[(size_t)(bx + ty + i) * R + by + tx] = (f16)tile[tx][ty + i];
}

// ---------------- per-chunk label histogram + global counts ----------------
__global__ __launch_bounds__(256) void hist_chunk_k(const int* __restrict__ labels,
                                                    int* __restrict__ counts,
                                                    int* __restrict__ chunkCnt) {
    __shared__ int hloc[NL];
    int t = threadIdx.x, c = blockIdx.x;
    if (t < NL) hloc[t] = 0;
    __syncthreads();
    atomicAdd(&hloc[labels[c * 256 + t]], 1);
    __syncthreads();
    if (t < NL) {
        chunkCnt[c * NL + t] = hloc[t];
        atomicAdd(&counts[t], hloc[t]);
    }
}

// ---------------- scan: baseC[c][l] = globalBase[l] + sum_{c'<c} chunkCnt[c'][l] ----------------
__global__ void scan_all_k(const int* __restrict__ chunkCnt, const int* __restrict__ counts,
                           int* __restrict__ baseC, int* __restrict__ baseG) {
    int l = threadIdx.x;    // 64 threads
    int gb = 0;
    for (int j = 0; j < l; ++j) gb += counts[j];
    baseG[l] = gb;
    int run = gb;
    for (int c = 0; c < 128; ++c) {
        baseC[c * NL + l] = run;
        run += chunkCnt[c * NL + l];
    }
}

// ---------------- fully parallel stable placement (order = (label, index)) ----------------
__global__ __launch_bounds__(256) void place_k(const int* __restrict__ labels,
                                               const int* __restrict__ baseC,
                                               int* __restrict__ indexArr) {
    __shared__ int labs[256];
    int t = threadIdx.x, c = blockIdx.x;
    int ii = c * 256 + t;
    int lab = labels[ii];
    labs[t] = lab;
    __syncthreads();
    int rank = 0;
    for (int j = 0; j < 256; ++j)
        rank += (j < t && labs[j] == lab) ? 1 : 0;      // LDS broadcast reads, deterministic
    indexArr[baseC[c * NL + lab] + rank] = ii;
}

// ---------------- gather rows of x via index, convert to f16 (sorted domain) ----------------
__global__ __launch_bounds__(256) void gather_cvt_k(const float4* __restrict__ x4,
                                                    const int* __restrict__ indexArr,
                                                    f16x4* __restrict__ xh4) {
    int t = threadIdx.x;
    int row = blockIdx.x * 2 + (t >> 7);
    int c4 = t & 127;
    int j = indexArr[row];
    float4 v = x4[(size_t)j * 128 + c4];
    f16x4 o = { (f16)v.x, (f16)v.y, (f16)v.z, (f16)v.w };
    xh4[(size_t)row * 128 + c4] = o;
}

// ---------------- f16 MFMA GEMM: C[M x BNTOT] = A[M x 512] @ BT[BNTOT x 512]^T ----------------
// Best-known: tile 128x256, BK=32, 8 waves (2M x 4N), square 64x64 wave tiles.
// 3-buffer rotation, one barrier per K-step, counted vmcnt(3), T2 source-side swizzle,
// T1 bijective XCD swizzle, swapped-operand vector epilogue. VGPR 64 -> 4 waves/SIMD.
// LEDGER CLOSED (R8-R22): six structural variants (2-buf drain0, counted 2-deep,
// square/3-buf/1-barrier, direct-global-B, 64x128 wave tiles, 256x256 deep-pipeline)
// all land at >= this config's 78us. 2-phase structure ceiling ~660 TF.
template<int BNTOT, bool OUT_F32, int NY>
__global__ __launch_bounds__(512, 4) void gemm_k512(const f16* __restrict__ A, const f16* __restrict__ BT,
                                                    void* __restrict__ Cout, const float* __restrict__ bias,
                                                    const int* __restrict__ scatterIdx) {
    constexpr int K = 512;
    constexpr int NKT = K / 32;             // 16 K-tiles
    __shared__ f16 As[3][128 * 32];         // 3 x 8 KB
    __shared__ f16 Bs[3][256 * 32];         // 3 x 16 KB  (72 KB total -> 2 blocks/CU)
    const int t = threadIdx.x;
    const int orig = blockIdx.x + gridDim.x * blockIdx.y;
    constexpr int NWG = 256 * NY;           // gridDim.x == 256 (N_TOK/128)
    constexpr int CPX = NWG / 8;
    const int lin = (orig & 7) * CPX + (orig >> 3);
    const int mBase = (lin / NY) * 128;
    const int nBase = (lin % NY) * 256;
    const int w = t >> 6, lane = t & 63;
    const int wm = w >> 2, wn = w & 3;      // 2 x 4 wave grid
    const int lr = lane & 15, lk = lane >> 4;
    const int kc = (lk ^ ((lr >> 1) & 3)) * 8;   // swizzled chunk offset (halves)
    f32x4 acc[4][4];
    #pragma unroll
    for (int m = 0; m < 4; ++m)
        #pragma unroll
        for (int n = 0; n < 4; ++n) acc[m][n] = (f32x4){0.f, 0.f, 0.f, 0.f};

    auto stage = [&](int buf, int kt) {
        {
            int id = t;
            int row = id >> 2, c = id & 3;
            int cg = c ^ ((row >> 1) & 3);
            GLOAD_LDS16(&A[(size_t)(mBase + row) * K + kt * 32 + cg * 8],
                        &As[buf][(size_t)(w * 64) * 8]);
        }
        #pragma unroll
        for (int r = 0; r < 2; ++r) {
            int id = r * 512 + t;
            int row = id >> 2, c = id & 3;
            int cg = c ^ ((row >> 1) & 3);
            GLOAD_LDS16(&BT[(size_t)(nBase + row) * K + kt * 32 + cg * 8],
                        &Bs[buf][(size_t)(r * 512 + w * 64) * 8]);
        }
    };
    auto compute = [&](int buf) {
        f16x8 af[4], bf[4];
        #pragma unroll
        for (int m = 0; m < 4; ++m)
            af[m] = *(const f16x8*)&As[buf][(wm * 64 + m * 16 + lr) * 32 + kc];
        #pragma unroll
        for (int n = 0; n < 4; ++n)
            bf[n] = *(const f16x8*)&Bs[buf][(wn * 64 + n * 16 + lr) * 32 + kc];
        #pragma unroll
        for (int m = 0; m < 4; ++m)
            #pragma unroll
            for (int n = 0; n < 4; ++n)
                acc[m][n] = __builtin_amdgcn_mfma_f32_16x16x32_f16(bf[n], af[m], acc[m][n], 0, 0, 0);
    };

    stage(0, 0);
    asm volatile("" ::: "memory");          // compiler fence: keep stage(0) DMAs oldest
    stage(1, 1);
    for (int kt = 0; kt < NKT; ++kt) {
        if (kt < NKT - 1) {
            asm volatile("s_waitcnt vmcnt(3)" ::: "memory");
        } else {
            asm volatile("s_waitcnt vmcnt(0)" ::: "memory");
        }
        __builtin_amdgcn_s_barrier();
        if (kt + 2 < NKT) stage((kt + 2) % 3, kt + 2);
        compute(kt % 3);
    }

    #pragma unroll
    for (int m = 0; m < 4; ++m) {
        int row = mBase + wm * 64 + m * 16 + lr;
        int srow = OUT_F32 ? scatterIdx[row] : row;
        #pragma unroll
        for (int n = 0; n < 4; ++n) {
            int col = nBase + wn * 64 + n * 16 + lk * 4;
            if constexpr (OUT_F32) {
                float4 bv = *(const float4*)&bias[col];
                float4 sv = make_float4(acc[m][n][0] + bv.x, acc[m][n][1] + bv.y,
                                        acc[m][n][2] + bv.z, acc[m][n][3] + bv.w);
                *(float4*)&((float*)Cout)[(size_t)srow * BNTOT + col] = sv;
            } else {
                f16x4 hv = { (f16)acc[m][n][0], (f16)acc[m][n][1],
                             (f16)acc[m][n][2], (f16)acc[m][n][3] };
                *(f16x4*)&((f16*)Cout)[(size_t)srow * BNTOT + col] = hv;
            }
        }
    }
}

// ---------------- segment-sum partials: grid (NL, 4), deterministic scratch ----------------
__global__ __launch_bounds__(256) void pool_part_k(const f16* __restrict__ qkvh,
                                                   const int* __restrict__ baseG,
                                                   const int* __restrict__ counts,
                                                   float* __restrict__ psum) {
    int l = blockIdx.x, g = blockIdx.y;
    int t = threadIdx.x;
    int c = t & 127, rg = t >> 7;
    int b0 = baseG[l];
    int cnt = counts[l];
    f32x4 a0 = {0.f,0.f,0.f,0.f}, a1 = {0.f,0.f,0.f,0.f};
    for (int p = g * 2 + rg; p < cnt; p += 8) {
        f16x8 v = *(const f16x8*)&qkvh[(size_t)(b0 + p) * QKVC + c * 8];
        a0[0] += (float)v[0]; a0[1] += (float)v[1]; a0[2] += (float)v[2]; a0[3] += (float)v[3];
        a1[0] += (float)v[4]; a1[1] += (float)v[5]; a1[2] += (float)v[6]; a1[3] += (float)v[7];
    }
    __shared__ f32x4 red[2][128][2];
    red[rg][c][0] = a0; red[rg][c][1] = a1;
    __syncthreads();
    if (t < 128) {
        f32x4 s0 = red[0][t][0] + red[1][t][0];
        f32x4 s1 = red[0][t][1] + red[1][t][1];
        size_t o = ((size_t)g * NL + l) * 1024 + t * 8;
        *(f32x4*)&psum[o] = s0;
        *(f32x4*)&psum[o + 4] = s1;
    }
}

// ---------------- pooling finalize: sum 4 partials, divide, emit f32 + f16 ----------------
__global__ __launch_bounds__(256) void pool_fin_k(const float* __restrict__ psum,
                                                  const int* __restrict__ counts,
                                                  float* __restrict__ ql, float* __restrict__ kl,
                                                  f16* __restrict__ qlh, f16* __restrict__ klh) {
    int l = blockIdx.x;
    int t = threadIdx.x;
    int bse = t * 4;
    float inv = 1.0f / (float)(counts[l] > 0 ? counts[l] : 1);
    f32x4 s = {0.f,0.f,0.f,0.f};
    #pragma unroll
    for (int g = 0; g < 4; ++g)
        s += *(const f32x4*)&psum[((size_t)g * NL + l) * 1024 + bse];
    s *= inv;
    f16x4 hv = { (f16)s[0], (f16)s[1], (f16)s[2], (f16)s[3] };
    if (bse < 512) {
        int h = bse >> 6, d0 = bse & 63;
        size_t o = ((size_t)(h * 64 + l)) * 64 + d0;
        *(f32x4*)&ql[o] = s;
        *(f16x4*)&qlh[o] = hv;
    } else {
        int bb = bse - 512;
        int h = bb >> 6, d0 = bb & 63;
        size_t o = ((size_t)(h * 64 + l)) * 64 + d0;
        *(f32x4*)&kl[o] = s;
        *(f16x4*)&klh[o] = hv;
    }
}

// ---------------- attn2 = softmax(ql@kl^T) rows; per-head row/col abs-sum maxes ----------------
__global__ __launch_bounds__(256) void attn2_k(const float* __restrict__ ql, const float* __restrict__ kl,
                                               float* __restrict__ a_out, float* __restrict__ mrow,
                                               float* __restrict__ mcol) {
    int h = blockIdx.x;
    __shared__ float qs[64][65], ks[64][65], a[64][65];
    __shared__ float red[64][4];
    __shared__ float rowv[64], colv[64];
    int t = threadIdx.x;
    for (int idx = t; idx < 4096; idx += 256) {
        int r = idx >> 6, c = idx & 63;
        qs[r][c] = ql[h * 4096 + idx];
        ks[r][c] = kl[h * 4096 + idx];
    }
    __syncthreads();
    int i = t >> 2, q4 = t & 3, j0 = q4 * 16;
    float o[16];
    #pragma unroll
    for (int jj = 0; jj < 16; ++jj) o[jj] = 0.f;
    for (int d = 0; d < 64; ++d) {
        float qv = qs[i][d];
        #pragma unroll
        for (int jj = 0; jj < 16; ++jj) o[jj] += qv * ks[j0 + jj][d];
    }
    float pmx = o[0];
    #pragma unroll
    for (int jj = 1; jj < 16; ++jj) pmx = fmaxf(pmx, o[jj]);
    red[i][q4] = pmx;
    __syncthreads();
    float rm = fmaxf(fmaxf(red[i][0], red[i][1]), fmaxf(red[i][2], red[i][3]));
    float psum = 0.f;
    #pragma unroll
    for (int jj = 0; jj < 16; ++jj) { o[jj] = expf(o[jj] - rm); psum += o[jj]; }
    __syncthreads();
    red[i][q4] = psum;
    __syncthreads();
    float rs = red[i][0] + red[i][1] + red[i][2] + red[i][3];
    float inv = 1.0f / rs;
    #pragma unroll
    for (int jj = 0; jj < 16; ++jj) { o[jj] *= inv; a[i][j0 + jj] = o[jj]; }
    __syncthreads();
    for (int idx = t; idx < 4096; idx += 256) a_out[h * 4096 + idx] = a[idx >> 6][idx & 63];
    float rsum = 0.f;
    #pragma unroll
    for (int jj = 0; jj < 16; ++jj) rsum += o[jj];
    __syncthreads();
    red[i][q4] = rsum;
    __syncthreads();
    if (q4 == 0) rowv[i] = red[i][0] + red[i][1] + red[i][2] + red[i][3];
    float csum = 0.f;
    #pragma unroll
    for (int jj = 0; jj < 16; ++jj) csum += a[j0 + jj][i];
    __syncthreads();
    red[i][q4] = csum;
    __syncthreads();
    if (q4 == 0) colv[i] = red[i][0] + red[i][1] + red[i][2] + red[i][3];
    __syncthreads();
    if (t == 0) {
        float mr = rowv[0], mc = colv[0];
        for (int j = 1; j < 64; ++j) { mr = fmaxf(mr, rowv[j]); mc = fmaxf(mc, colv[j]); }
        mrow[h] = mr; mcol[h] = mc;
    }
}

// ---------------- fused attn3 + pinv-NS (block x==0 = pinv; x=1..64 = attn3 chunks) ----------------
__global__ __launch_bounds__(256) void attn3_pinv_k(const f16* __restrict__ qkvh,
                                                    const f16* __restrict__ qlh,
                                                    float* __restrict__ pm, float* __restrict__ ps,
                                                    float* __restrict__ pacc,
                                                    const float* __restrict__ a_g,
                                                    const float* __restrict__ mrow,
                                                    const float* __restrict__ mcol,
                                                    float* __restrict__ zg) {
    union ShU {
        struct { f16 Qls[64 * 64]; f16 Ks[64 * 64]; f16 vT[64 * 72]; f16 Ps[64 * 72]; float fsh[64]; } a3;
        struct { f16 zRh[64][72], zRl[64][72], cRh[64][72], cRl[64][72],
                 Xh[64][72], Xl[64][72], Yh[64][72], Yl[64][72]; } pv;
    };
    __shared__ ShU sh;
    const int t = threadIdx.x;
    const int w = t >> 6, lane = t & 63;
    const int lr = lane & 15;
    const int h = blockIdx.y;

    if (blockIdx.x == 0) {
        const int lk = lane >> 4;
        f16 (&zRh)[64][72] = sh.pv.zRh; f16 (&zRl)[64][72] = sh.pv.zRl;
        f16 (&cRh)[64][72] = sh.pv.cRh; f16 (&cRl)[64][72] = sh.pv.cRl;
        f16 (&Xh)[64][72]  = sh.pv.Xh;  f16 (&Xl)[64][72]  = sh.pv.Xl;
        f16 (&Yh)[64][72]  = sh.pv.Yh;  f16 (&Yl)[64][72]  = sh.pv.Yl;
        float mr = mrow[0], mc = mcol[0];
        #pragma unroll
        for (int k = 1; k < 8; ++k) { mr = fmaxf(mr, mrow[k]); mc = fmaxf(mc, mcol[k]); }
        const float inv0 = 1.0f / (mr * mc);
        for (int idx = t; idx < 4096; idx += 256) {
            int r = idx >> 6, c = idx & 63;
            float zv = a_g[h * 4096 + idx] * inv0;
            f16 hv = (f16)zv;
            zRh[c][r] = hv; zRl[c][r] = (f16)(zv - (float)hv);
        }
        __syncthreads();

        f32x4 po[4];
        auto product = [&](const f16 (*Lh)[72], const f16 (*Ll)[72],
                           const f16 (*Rh)[72], const f16 (*Rl)[72]) {
            #pragma unroll
            for (int n = 0; n < 4; ++n) po[n] = (f32x4){0.f, 0.f, 0.f, 0.f};
            #pragma unroll
            for (int ck = 0; ck < 2; ++ck) {
                f16x8 axh = *(const f16x8*)&Lh[w * 16 + lr][ck * 32 + lk * 8];
                f16x8 axl = *(const f16x8*)&Ll[w * 16 + lr][ck * 32 + lk * 8];
                #pragma unroll
                for (int n = 0; n < 4; ++n) {
                    f16x8 byh = *(const f16x8*)&Rh[n * 16 + lr][ck * 32 + lk * 8];
                    f16x8 byl = *(const f16x8*)&Rl[n * 16 + lr][ck * 32 + lk * 8];
                    po[n] = __builtin_amdgcn_mfma_f32_16x16x32_f16(byh, axh, po[n], 0, 0, 0);
                    po[n] = __builtin_amdgcn_mfma_f32_16x16x32_f16(byl, axh, po[n], 0, 0, 0);
                    po[n] = __builtin_amdgcn_mfma_f32_16x16x32_f16(byh, axl, po[n], 0, 0, 0);
                }
            }
        };

        for (int it = 0; it < 6; ++it) {
            for (int idx = t; idx < 4096; idx += 256) {
                int r = idx >> 6, c = idx & 63;
                float av = a_g[h * 4096 + idx];
                f16 ah = (f16)av;
                Xh[r][c] = ah; Xl[r][c] = (f16)(av - (float)ah);
                float zv = (float)zRh[r][c] + (float)zRl[r][c];
                f16 zh = (f16)zv;
                Yh[c][r] = zh; Yl[c][r] = (f16)(zv - (float)zh);
            }
            __syncthreads();
            product(Xh, Xl, Yh, Yl);                       // C = a @ z
            __syncthreads();
            #pragma unroll
            for (int n = 0; n < 4; ++n)
                #pragma unroll
                for (int j = 0; j < 4; ++j) {
                    int r = w * 16 + lr, c = n * 16 + lk * 4 + j;
                    float v = po[n][j]; f16 hv = (f16)v; f16 lv = (f16)(v - (float)hv);
                    cRh[r][c] = hv; cRl[r][c] = lv;
                    Xh[c][r] = hv;  Xl[c][r] = lv;
                }
            __syncthreads();
            product(cRh, cRl, Xh, Xl);                     // C @ C
            #pragma unroll
            for (int n = 0; n < 4; ++n)
                #pragma unroll
                for (int j = 0; j < 4; ++j) {
                    int r = w * 16 + lr, c = n * 16 + lk * 4 + j;
                    float v = 7.f * ((float)cRh[r][c] + (float)cRl[r][c]) - po[n][j];
                    f16 hv = (f16)v;
                    Yh[c][r] = hv; Yl[c][r] = (f16)(v - (float)hv);
                }
            __syncthreads();
            product(cRh, cRl, Yh, Yl);                     // C @ D
            #pragma unroll
            for (int n = 0; n < 4; ++n)
                #pragma unroll
                for (int j = 0; j < 4; ++j) {
                    int r = w * 16 + lr, c = n * 16 + lk * 4 + j;
                    float v = 15.f * ((float)cRh[r][c] + (float)cRl[r][c]) - po[n][j];
                    f16 hv = (f16)v;
                    Xh[c][r] = hv; Xl[c][r] = (f16)(v - (float)hv);
                }
            __syncthreads();
            product(zRh, zRl, Xh, Xl);                     // z @ E
            #pragma unroll
            for (int n = 0; n < 4; ++n)
                #pragma unroll
                for (int j = 0; j < 4; ++j) {
                    int r = w * 16 + lr, c = n * 16 + lk * 4 + j;
                    float v = 0.25f * (13.f * ((float)zRh[r][c] + (float)zRl[r][c]) - po[n][j]);
                    f16 hv = (f16)v;
                    zRh[r][c] = hv; zRl[r][c] = (f16)(v - (float)hv);
                }
            __syncthreads();
        }
        for (int idx = t; idx < 4096; idx += 256) {
            int r = idx >> 6, c = idx & 63;
            zg[h * 4096 + idx] = (float)zRh[r][c] + (float)zRl[r][c];
        }
        return;
    }

    // ---------------- attn3 flash path ----------------
    const int cx = blockIdx.x - 1;
    const int hi = lane >> 4;
    f16* Qls = sh.a3.Qls;
    f16* Ks  = sh.a3.Ks;
    f16* vT  = sh.a3.vT;
    f16* Ps  = sh.a3.Ps;
    float* fsh = sh.a3.fsh;

    #pragma unroll
    for (int pss = 0; pss < 2; ++pss) {
        int q = pss * 256 + t;
        int r = q >> 3, cs = (q & 7) ^ (r & 7);
        GLOAD_LDS16(&qlh[(size_t)h * 4096 + r * 64 + cs * 8], &Qls[(size_t)(pss * 256 + w * 64) * 8]);
    }
    float m_reg = -1e30f, s_reg = 0.f;
    f32x4 accT[4];
    #pragma unroll
    for (int lf = 0; lf < 4; ++lf) accT[lf] = (f32x4){0.f, 0.f, 0.f, 0.f};

    const int vk8 = t & 7, vnn = t >> 3;

    for (int sub = 0; sub < 8; ++sub) {
        const int n0 = cx * 512 + sub * 64;
        __syncthreads();
        #pragma unroll
        for (int pss = 0; pss < 2; ++pss) {
            int q = pss * 256 + t;
            int r = q >> 3, cs = (q & 7) ^ (r & 7);
            GLOAD_LDS16(&qkvh[(size_t)(n0 + r) * QKVC + 512 + h * 64 + cs * 8],
                        &Ks[(size_t)(pss * 256 + w * 64) * 8]);
        }
        #pragma unroll
        for (int p2 = 0; p2 < 2; ++p2) {
            int n = vnn + 32 * p2;
            f16x8 rv = *(const f16x8*)&qkvh[(size_t)(n0 + n) * QKVC + 1024 + h * 64 + vk8 * 8];
            #pragma unroll
            for (int i = 0; i < 8; ++i) {
                int e = i ^ vk8;
                vT[(vk8 * 8 + e) * 72 + n] = rv[e];
            }
        }
        __syncthreads();
        f32x4 c[4];
        #pragma unroll
        for (int kf = 0; kf < 4; ++kf) c[kf] = (f32x4){0.f, 0.f, 0.f, 0.f};
        const int lq = w * 16 + lr;
        #pragma unroll
        for (int ks = 0; ks < 2; ++ks) {
            f16x8 bf = *(const f16x8*)&Qls[lq * 64 + (((ks * 4 + hi) ^ (lq & 7)) * 8)];
            #pragma unroll
            for (int kf = 0; kf < 4; ++kf) {
                int rn = kf * 16 + lr;
                f16x8 af = *(const f16x8*)&Ks[rn * 64 + (((ks * 4 + hi) ^ (rn & 7)) * 8)];
                c[kf] = __builtin_amdgcn_mfma_f32_16x16x32_f16(af, bf, c[kf], 0, 0, 0);
            }
        }
        float tmax = -1e30f;
        #pragma unroll
        for (int kf = 0; kf < 4; ++kf)
            #pragma unroll
            for (int j = 0; j < 4; ++j) tmax = fmaxf(tmax, c[kf][j]);
        tmax = fmaxf(tmax, __shfl_xor(tmax, 16));
        tmax = fmaxf(tmax, __shfl_xor(tmax, 32));
        float newm = fmaxf(m_reg, tmax);
        float fct = __expf(m_reg - newm);
        float psum = 0.f;
        #pragma unroll
        for (int kf = 0; kf < 4; ++kf) {
            f16x4 pk;
            #pragma unroll
            for (int j = 0; j < 4; ++j) {
                float e = __expf(c[kf][j] - newm);
                psum += e;
                pk[j] = (f16)e;
            }
            *(f16x4*)&Ps[lq * 72 + kf * 16 + hi * 4] = pk;
        }
        psum += __shfl_xor(psum, 16);
        psum += __shfl_xor(psum, 32);
        s_reg = s_reg * fct + psum;
        m_reg = newm;
        if (hi == 0) fsh[lq] = fct;
        __syncthreads();
        #pragma unroll
        for (int lf = 0; lf < 4; ++lf) {
            f32x4 fr = *(const f32x4*)&fsh[lf * 16 + hi * 4];
            accT[lf] *= fr;
        }
        #pragma unroll
        for (int ks = 0; ks < 2; ++ks) {
            f16x8 bf = *(const f16x8*)&vT[(w * 16 + lr) * 72 + ks * 32 + hi * 8];
            #pragma unroll
            for (int lf = 0; lf < 4; ++lf) {
                f16x8 af = *(const f16x8*)&Ps[(lf * 16 + lr) * 72 + ks * 32 + hi * 8];
                accT[lf] = __builtin_amdgcn_mfma_f32_16x16x32_f16(af, bf, accT[lf], 0, 0, 0);
            }
        }
    }
    int part = h * NCHUNK + cx;
    if (hi == 0) {
        pm[part * 64 + w * 16 + lr] = m_reg;
        ps[part * 64 + w * 16 + lr] = s_reg;
    }
    #pragma unroll
    for (int lf = 0; lf < 4; ++lf)
        #pragma unroll
        for (int j = 0; j < 4; ++j)
            pacc[((size_t)part * 64 + (lf * 16 + hi * 4 + j)) * 64 + (w * 16 + lr)] = accT[lf][j];
}

// ---------------- merge attn3 partials -> T[h][l][d] ----------------
__global__ void attn3_merge_k(const float* __restrict__ pm, const float* __restrict__ ps,
                              const float* __restrict__ pacc, float* __restrict__ T) {
    int l = blockIdx.x, h = blockIdx.y, d = threadIdx.x;
    float m = -1e30f;
    for (int c = 0; c < NCHUNK; ++c) m = fmaxf(m, pm[(h * NCHUNK + c) * 64 + l]);
    float s = 0.f, a = 0.f;
    for (int c = 0; c < NCHUNK; ++c) {
        float wgt = __expf(pm[(h * NCHUNK + c) * 64 + l] - m);
        s += ps[(h * NCHUNK + c) * 64 + l] * wgt;
        a += pacc[((size_t)(h * NCHUNK + c) * 64 + l) * 64 + d] * wgt;
    }
    T[(h * 64 + l) * 64 + d] = a / s;
}

// ---------------- final product M = z @ T (hi/lo MFMA), emit M^T hi/lo f16 ----------------
__global__ __launch_bounds__(256) void zmatT_fin_k(const float* __restrict__ zg,
                                                   const float* __restrict__ T,
                                                   f16* __restrict__ MthHi, f16* __restrict__ MthLo) {
    const int h = blockIdx.x;
    __shared__ f16 zFh[64][72], zFl[64][72], tCh[64][72], tCl[64][72];
    const int t = threadIdx.x;
    const int w = t >> 6, lane = t & 63;
    const int lr = lane & 15, lk = lane >> 4;
    for (int idx = t; idx < 4096; idx += 256) {
        int r = idx >> 6, c = idx & 63;
        float zv = zg[h * 4096 + idx]; f16 zh = (f16)zv;
        zFh[r][c] = zh; zFl[r][c] = (f16)(zv - (float)zh);
        float tv = T[h * 4096 + idx]; f16 th = (f16)tv;
        tCh[c][r] = th; tCl[c][r] = (f16)(tv - (float)th);
    }
    __syncthreads();
    f32x4 po[4];
    #pragma unroll
    for (int n = 0; n < 4; ++n) po[n] = (f32x4){0.f, 0.f, 0.f, 0.f};
    #pragma unroll
    for (int ck = 0; ck < 2; ++ck) {
        f16x8 axh = *(const f16x8*)&zFh[w * 16 + lr][ck * 32 + lk * 8];
        f16x8 axl = *(const f16x8*)&zFl[w * 16 + lr][ck * 32 + lk * 8];
        #pragma unroll
        for (int n = 0; n < 4; ++n) {
            f16x8 byh = *(const f16x8*)&tCh[n * 16 + lr][ck * 32 + lk * 8];
            f16x8 byl = *(const f16x8*)&tCl[n * 16 + lr][ck * 32 + lk * 8];
            po[n] = __builtin_amdgcn_mfma_f32_16x16x32_f16(byh, axh, po[n], 0, 0, 0);
            po[n] = __builtin_amdgcn_mfma_f32_16x16x32_f16(byl, axh, po[n], 0, 0, 0);
            po[n] = __builtin_amdgcn_mfma_f32_16x16x32_f16(byh, axl, po[n], 0, 0, 0);
        }
    }
    #pragma unroll
    for (int n = 0; n < 4; ++n)
        #pragma unroll
        for (int j = 0; j < 4; ++j) {
            int r = w * 16 + lr, c = n * 16 + lk * 4 + j;
            float v = po[n][j]; f16 hv = (f16)v;
            MthHi[h * 4096 + c * 64 + r] = hv;             // transposed layout [h][d][l]
            MthLo[h * 4096 + c * 64 + r] = (f16)(v - (float)hv);
        }
}

// ---------------- fused attn1 + depthwise conv: softmax(Q@kl^T)@M + conv(v) -> Yh ----------------
__global__ __launch_bounds__(256) void attn1_k(const f16* __restrict__ qkvh, const f16* __restrict__ klh,
                                               const f16* __restrict__ MthHi, const f16* __restrict__ MthLo,
                                               const float* __restrict__ resk, f16* __restrict__ Yh) {
    const int h = blockIdx.y;
    const int p0 = blockIdx.x * 128;
    const int t = threadIdx.x;
    const int w = t >> 6, lane = t & 63;
    const int lr = lane & 15, hi = lane >> 4;
    __shared__ f16 QPs[128][72];     // Q tile -> P tile -> O tile (wave-private rows)
    __shared__ f16 Ks[64][72];
    __shared__ f16 Mhi[64][72];
    __shared__ f16 Mlo[64][72];
    __shared__ f16 vt[160][72];      // v rows [p0-16, p0+144)

    #pragma unroll
    for (int i = 0; i < 4; ++i) {
        int id = i * 256 + t, row = id >> 3, c8 = id & 7;
        *(f16x8*)&QPs[row][c8 * 8] = *(const f16x8*)&qkvh[(size_t)(p0 + row) * QKVC + h * 64 + c8 * 8];
    }
    #pragma unroll
    for (int i = 0; i < 2; ++i) {
        int id = i * 256 + t, row = id >> 3, c8 = id & 7;
        *(f16x8*)&Ks[row][c8 * 8]  = *(const f16x8*)&klh[h * 4096 + id * 8];
        *(f16x8*)&Mhi[row][c8 * 8] = *(const f16x8*)&MthHi[h * 4096 + id * 8];
        *(f16x8*)&Mlo[row][c8 * 8] = *(const f16x8*)&MthLo[h * 4096 + id * 8];
    }
    for (int id = t; id < 160 * 8; id += 256) {
        int rr = id >> 3, c8 = id & 7;
        int pg = p0 - 16 + rr;
        int4 v = {0, 0, 0, 0};
        if (pg >= 0 && pg < N_TOK)
            v = *(const int4*)&qkvh[(size_t)pg * QKVC + 1024 + h * 64 + c8 * 8];
        *(int4*)&vt[rr][c8 * 8] = v;
    }
    float wk[KSZ];
    #pragma unroll
    for (int k = 0; k < KSZ; ++k) wk[k] = resk[h * KSZ + k];
    __syncthreads();

    f32x4 c[4][2];
    #pragma unroll
    for (int lf = 0; lf < 4; ++lf)
        #pragma unroll
        for (int nf = 0; nf < 2; ++nf) c[lf][nf] = (f32x4){0.f, 0.f, 0.f, 0.f};
    #pragma unroll
    for (int ks = 0; ks < 2; ++ks) {
        f16x8 af[4], bf[2];
        #pragma unroll
        for (int lf = 0; lf < 4; ++lf) af[lf] = *(const f16x8*)&Ks[lf * 16 + lr][ks * 32 + hi * 8];
        #pragma unroll
        for (int nf = 0; nf < 2; ++nf) bf[nf] = *(const f16x8*)&QPs[w * 32 + nf * 16 + lr][ks * 32 + hi * 8];
        #pragma unroll
        for (int lf = 0; lf < 4; ++lf)
            #pragma unroll
            for (int nf = 0; nf < 2; ++nf)
                c[lf][nf] = __builtin_amdgcn_mfma_f32_16x16x32_f16(af[lf], bf[nf], c[lf][nf], 0, 0, 0);
    }

    #pragma unroll
    for (int nf = 0; nf < 2; ++nf) {
        float m = -1e30f;
        #pragma unroll
        for (int lf = 0; lf < 4; ++lf)
            #pragma unroll
            for (int j = 0; j < 4; ++j) m = fmaxf(m, c[lf][nf][j]);
        m = fmaxf(m, __shfl_xor(m, 16));
        m = fmaxf(m, __shfl_xor(m, 32));
        float s = 0.f;
        #pragma unroll
        for (int lf = 0; lf < 4; ++lf)
            #pragma unroll
            for (int j = 0; j < 4; ++j) { float e = __expf(c[lf][nf][j] - m); c[lf][nf][j] = e; s += e; }
        s += __shfl_xor(s, 16);
        s += __shfl_xor(s, 32);
        float inv = 1.0f / s;
        #pragma unroll
        for (int lf = 0; lf < 4; ++lf) {
            f16x4 pk;
            #pragma unroll
            for (int j = 0; j < 4; ++j) pk[j] = (f16)(c[lf][nf][j] * inv);
            *(f16x4*)&QPs[w * 32 + nf * 16 + lr][lf * 16 + hi * 4] = pk;
        }
    }

    f32x4 o[2][4];
    #pragma unroll
    for (int nf = 0; nf < 2; ++nf)
        #pragma unroll
        for (int df = 0; df < 4; ++df) o[nf][df] = (f32x4){0.f, 0.f, 0.f, 0.f};
    #pragma unroll
    for (int ks = 0; ks < 2; ++ks) {
        f16x8 pa[2], bh[4], bl[4];
        #pragma unroll
        for (int nf = 0; nf < 2; ++nf) pa[nf] = *(const f16x8*)&QPs[w * 32 + nf * 16 + lr][ks * 32 + hi * 8];
        #pragma unroll
        for (int df = 0; df < 4; ++df) {
            bh[df] = *(const f16x8*)&Mhi[df * 16 + lr][ks * 32 + hi * 8];
            bl[df] = *(const f16x8*)&Mlo[df * 16 + lr][ks * 32 + hi * 8];
        }
        #pragma unroll
        for (int nf = 0; nf < 2; ++nf)
            #pragma unroll
            for (int df = 0; df < 4; ++df) {
                o[nf][df] = __builtin_amdgcn_mfma_f32_16x16x32_f16(pa[nf], bh[df], o[nf][df], 0, 0, 0);
                o[nf][df] = __builtin_amdgcn_mfma_f32_16x16x32_f16(pa[nf], bl[df], o[nf][df], 0, 0, 0);
            }
    }

    #pragma unroll
    for (int nf = 0; nf < 2; ++nf)
        #pragma unroll
        for (int df = 0; df < 4; ++df)
            #pragma unroll
            for (int j = 0; j < 4; ++j)
                QPs[w * 32 + nf * 16 + hi * 4 + j][df * 16 + lr] = (f16)(o[nf][df][j]);
    __syncthreads();

    // vectorized conv + combine: thread owns a column PAIR (f16x2 reads, half the LDS instrs)
    const int d2 = t & 31, rg8 = t >> 5;
    const int r0 = rg8 * 16;
    float c0[48], c1[48];
    #pragma unroll
    for (int j = 0; j < 48; ++j) {
        f16x2 v = *(const f16x2*)&vt[r0 + j][d2 * 2];
        c0[j] = (float)v[0]; c1[j] = (float)v[1];
    }
    #pragma unroll
    for (int pp = 0; pp < 16; ++pp) {
        float a0 = 0.f, a1 = 0.f;
        #pragma unroll
        for (int k = 0; k < KSZ; ++k) { a0 += wk[k] * c0[pp + k]; a1 += wk[k] * c1[pp + k]; }
        int row = r0 + pp;
        f16x2 qv = *(const f16x2*)&QPs[row][d2 * 2];
        f16x2 ov;
        ov[0] = (f16)(a0 + (float)qv[0]);
        ov[1] = (f16)(a1 + (float)qv[1]);
        *(f16x2*)&Yh[(size_t)(p0 + row) * 512 + h * 64 + d2 * 2] = ov;
    }
}

// ---------------- host launch ----------------
extern "C" void kernel_launch(void* const* d_in, const int* in_sizes, int n_in,
                              void* d_out, int out_size, void* d_ws, size_t ws_size,
                              hipStream_t stream) {
    const float* x    = (const float*)d_in[0];
    const float* Wqkv = (const float*)d_in[1];
    const float* Wout = (const float*)d_in[2];
    const float* bout = (const float*)d_in[3];
    const float* resk = (const float*)d_in[4];
    const int*   labels = (const int*)d_in[5];
    float* out = (float*)d_out;

    char* w = (char*)d_ws;
    size_t off = 0;
    auto alloc = [&](size_t bytes) {
        void* p = w + off;
        off += (bytes + 255) & ~(size_t)255;
        return p;
    };
    f16* xh     = (f16*)alloc((size_t)N_TOK * DIMC * 2);       // sorted
    f16* qkvh   = (f16*)alloc((size_t)N_TOK * QKVC * 2);       // sorted
    f16* WqkvT  = (f16*)alloc((size_t)QKVC * DIMC * 2);
    f16* WoutT  = (f16*)alloc((size_t)DIMC * DIMC * 2);
    f16* Yh     = (f16*)alloc((size_t)N_TOK * DIMC * 2);       // sorted
    int* counts = (int*)alloc(NL * 4);
    int* chunkCnt = (int*)alloc((size_t)128 * NL * 4);
    int* baseC  = (int*)alloc((size_t)128 * NL * 4);
    int* baseG  = (int*)alloc(NL * 4);
    int* indexA = (int*)alloc((size_t)N_TOK * 4);
    float* ql   = (float*)alloc((size_t)NH * 64 * 64 * 4);
    float* kl   = (float*)alloc((size_t)NH * 64 * 64 * 4);
    f16* qlh    = (f16*)alloc((size_t)NH * 64 * 64 * 2);
    f16* klh    = (f16*)alloc((size_t)NH * 64 * 64 * 2);
    float* a2   = (float*)alloc((size_t)NH * 64 * 64 * 4);
    float* mrow = (float*)alloc(NH * 4);
    float* mcol = (float*)alloc(NH * 4);
    float* Tb   = (float*)alloc((size_t)NH * 64 * 64 * 4);
    float* zg   = (float*)alloc((size_t)NH * 64 * 64 * 4);
    f16* MthHi  = (f16*)alloc((size_t)NH * 64 * 64 * 2);
    f16* MthLo  = (f16*)alloc((size_t)NH * 64 * 64 * 2);
    float* pm   = (float*)alloc((size_t)NH * NCHUNK * 64 * 4);
    float* ps   = (float*)alloc((size_t)NH * NCHUNK * 64 * 4);
    float* pacc = (float*)alloc((size_t)NH * NCHUNK * 64 * 64 * 4);
    float* psum = (float*)alloc((size_t)4 * NL * 1024 * 4);    // 1 MB pooling partials

    hipMemsetAsync(counts, 0, NL * 4, stream);

    // parallel stable counting sort: chunk hist -> scan -> parallel placement
    hist_chunk_k<<<128, 256, 0, stream>>>(labels, counts, chunkCnt);
    scan_all_k<<<1, 64, 0, stream>>>(chunkCnt, counts, baseC, baseG);
    place_k<<<128, 256, 0, stream>>>(labels, baseC, indexA);
    // gather+convert x rows into sorted order
    gather_cvt_k<<<N_TOK / 2, 256, 0, stream>>>((const float4*)x, indexA, (f16x4*)xh);
    // weight transposes
    transpose_k<<<dim3(QKVC / 32, DIMC / 32), dim3(32, 8), 0, stream>>>(Wqkv, WqkvT, DIMC, QKVC);
    transpose_k<<<dim3(DIMC / 32, DIMC / 32), dim3(32, 8), 0, stream>>>(Wout, WoutT, DIMC, DIMC);
    // qkv = x_sorted @ Wqkv  (sorted domain)
    gemm_k512<QKVC, false, 6><<<dim3(N_TOK / 128, QKVC / 256), 512, 0, stream>>>(xh, WqkvT, qkvh, nullptr, nullptr);
    // segment pooling: 4-way partials (256 blocks) + finalize
    pool_part_k<<<dim3(NL, 4), 256, 0, stream>>>(qkvh, baseG, counts, psum);
    pool_fin_k<<<NL, 256, 0, stream>>>(psum, counts, ql, kl, qlh, klh);
    // attn2 (produces a2, mrow, mcol for pinv)
    attn2_k<<<NH, 256, 0, stream>>>(ql, kl, a2, mrow, mcol);
    // fused: attn3 flash chunks (x=1..64) + pinv NS iterations (x=0)
    attn3_pinv_k<<<dim3(NCHUNK + 1, NH), 256, 0, stream>>>(qkvh, qlh, pm, ps, pacc, a2, mrow, mcol, zg);
    attn3_merge_k<<<dim3(NL, NH), 64, 0, stream>>>(pm, ps, pacc, Tb);
    // final M^T = (z@T)^T in hi/lo f16
    zmatT_fin_k<<<NH, 256, 0, stream>>>(zg, Tb, MthHi, MthLo);
    // fused attn1 + depthwise conv -> Yh (sorted)
    attn1_k<<<dim3(N_TOK / 128, NH), 256, 0, stream>>>(qkvh, klh, MthHi, MthLo, resk, Yh);
    // final projection + bias, scatter rows back to original order
    gemm_k512<DIMC, true, 2><<<dim3(N_TOK / 128, DIMC / 256), 512, 0, stream>>>(Yh, WoutT, out, bout, indexA);
}